// Round 2
// baseline (13662.624 us; speedup 1.0000x reference)
//
#include <hip/hip_runtime.h>
#include <stdint.h>
#include <stddef.h>

// ---------------------------------------------------------------------------
// LSTM (B=64, T=1024, I=256, H=512) + attention pooling on MI355X (gfx950).
//   k_prep_x : x [B,T,I] fp32  -> xT [T][I/8][B][8] fp16 (MFMA B-layout)
//   k_prep_w : W_attn fp32     -> WaT [H/8][H][8] fp16  (MFMA B-layout)
//   k_lstm   : persistent recurrence, 256 blocks x 128 thr (1 block/CU),
//              W_hh and W_ih A-fragments in registers, fused x-projection
//              (computed for t+1 before the barrier), monotone-counter
//              agent-scope barrier with explicit release/acquire fences
//              (per-XCD L2 non-coherence!).
//   k_attn   : E[t*64+b][h] = exp(tanh(hs @ W_attn^T + b_attn)) fp16
//   k_pool   : partial softmax-pool over T chunks
//   k_final  : context[b][h] = num/den  (fp32 out)
// Workspace (~136 MB): [regionA: max(xT 32MB, E 64MB)][hs 67MB][WaT][pnum][pden][bar]
// ---------------------------------------------------------------------------

typedef _Float16 f16_t;
typedef _Float16 half8 __attribute__((ext_vector_type(8)));
typedef float f32x4 __attribute__((ext_vector_type(4)));

#define MFMA16(a, b, c) __builtin_amdgcn_mfma_f32_16x16x32_f16((a), (b), (c), 0, 0, 0)

static constexpr int BATCH = 64;
static constexpr int TLEN = 1024;
static constexpr int IDIM = 256;
static constexpr int HDIM = 512;

__device__ __forceinline__ float sigf(float x) { return 1.f / (1.f + __expf(-x)); }
// overflow-safe tanh
__device__ __forceinline__ float tanh_fast(float x) {
  float e = __expf(2.f * fabsf(x));
  float t = 1.f - 2.f / (e + 1.f);
  return copysignf(t, x);
}
// load 8 consecutive fp32 -> fp16x8 fragment
__device__ __forceinline__ half8 load_cvt8(const float* p) {
  f32x4 a = *(const f32x4*)p;
  f32x4 b = *(const f32x4*)(p + 4);
  half8 r;
#pragma unroll
  for (int j = 0; j < 4; ++j) { r[j] = (f16_t)a[j]; r[4 + j] = (f16_t)b[j]; }
  return r;
}

// ---------------------------------------------------------------------------
// xT[t][kk4][b][8] = (fp16) x[b][t][kk4*8+j]    (kk4 = 0..31)
// One block per t. Stage the 64x256 fp32 slice through LDS (coalesced reads),
// emit coalesced 16B writes in B-fragment order.
// ---------------------------------------------------------------------------
__global__ __launch_bounds__(256) void k_prep_x(const float* __restrict__ x,
                                                f16_t* __restrict__ xT) {
  __shared__ f16_t sx[64][IDIM + 8];   // +8 pad: break LDS bank aliasing
  const int t = blockIdx.x;
  const int tid = threadIdx.x;
#pragma unroll 4
  for (int b = 0; b < 64; ++b)
    sx[b][tid] = (f16_t)x[((size_t)b * TLEN + t) * IDIM + tid];
  __syncthreads();
#pragma unroll
  for (int it = 0; it < 8; ++it) {
    const int c = it * 256 + tid;      // c = kk4*64 + b
    const int b = c & 63, kk4 = c >> 6;
    half8 v = *(const half8*)&sx[b][kk4 * 8];
    *(half8*)(xT + (((size_t)t * 32 + kk4) * 64 + b) * 8) = v;
  }
}

// WaT[kk4][n][8] = (fp16) W_attn[n][kk4*8+j]    (kk4 = 0..63, n = 0..511)
__global__ __launch_bounds__(256) void k_prep_w(const float* __restrict__ Wa,
                                                f16_t* __restrict__ WaT) {
  const int id = blockIdx.x * 256 + threadIdx.x;   // 0..32767
  const int n = id & 511, kk4 = id >> 9;
  half8 v = load_cvt8(&Wa[(size_t)n * HDIM + kk4 * 8]);
  *(half8*)(WaT + ((size_t)kk4 * HDIM + n) * 8) = v;
}

// ---------------------------------------------------------------------------
// Recurrence. Block j (j=0..255): units u0=4*(j>>1)..+3, batch-half j&1.
// Wave w handles batches b = (j&1)*32 + w*16 + col. M rows ordered
// [unit][gate]: C row q*4+r -> unit q, gate r, so the whole gate/cell update
// is lane-local with c in an fp32 register for all 1024 steps.
// hs: [1025][64][512] fp16 slabs; slab t-1 read, slab t written.
// ---------------------------------------------------------------------------
__global__ __launch_bounds__(128) void k_lstm(
    const float* __restrict__ Whh, const float* __restrict__ Wih,
    const float* __restrict__ bih, const float* __restrict__ bhh,
    const f16_t* __restrict__ xT, f16_t* __restrict__ hs,
    unsigned int* __restrict__ bar) {
  const int tid = threadIdx.x;
  const int w = tid >> 6;
  const int L = tid & 63;
  const int q = L >> 4, col = L & 15;
  const int u0 = (blockIdx.x >> 1) * 4;
  const int b = (blockIdx.x & 1) * 32 + w * 16 + col;
  const int myu = u0 + q;

  // Persistent A-fragments. A[m=lane&15][k=q*8+j]; m = unit_local*4 + gate.
  const int am = col;
  const int arow = (am & 3) * HDIM + u0 + (am >> 2);   // global W row
  half8 wAh[16], wAx[8];
#pragma unroll
  for (int kk = 0; kk < 16; ++kk)
    wAh[kk] = load_cvt8(&Whh[(size_t)arow * HDIM + kk * 32 + q * 8]);
#pragma unroll
  for (int kk = 0; kk < 8; ++kk)
    wAx[kk] = load_cvt8(&Wih[(size_t)arow * IDIM + kk * 32 + q * 8]);

  float pb[4];
#pragma unroll
  for (int r = 0; r < 4; ++r) pb[r] = bih[r * HDIM + myu] + bhh[r * HDIM + myu];

  // x-projection for step t (uses xT only, no cross-block dependency)
  auto xgemm = [&](int t) {
    f32x4 a = {0.f, 0.f, 0.f, 0.f};
#pragma unroll
    for (int kk = 0; kk < 8; ++kk) {
      half8 bf = *(const half8*)(xT +
          (((size_t)(t - 1) * 32 + kk * 4 + q) * 64 + b) * 8);
      a = MFMA16(wAx[kk], bf, a);
    }
    return a;
  };

  float c = 0.f;
  f32x4 xacc = xgemm(1);
  for (int t = 1; t <= TLEN; ++t) {
    const f16_t* hprev = hs + ((size_t)(t - 1) * BATCH + b) * HDIM;
    f32x4 acc = xacc;
#pragma unroll
    for (int kk = 0; kk < 16; ++kk) {        // K = 512
      half8 bfr = *(const half8*)(hprev + kk * 32 + q * 8);
      acc = MFMA16(wAh[kk], bfr, acc);
    }
    const float ig = sigf(acc[0] + pb[0]);
    const float fg = sigf(acc[1] + pb[1]);
    const float gg = tanh_fast(acc[2] + pb[2]);
    const float og = sigf(acc[3] + pb[3]);
    c = fg * c + ig * gg;
    const float hval = og * tanh_fast(c);
    hs[((size_t)t * BATCH + b) * HDIM + myu] = (f16_t)hval;

    // x-projection for the NEXT step: overlaps with the barrier wait below
    if (t < TLEN) xacc = xgemm(t + 1);

    // ---- device-scope barrier (monotone counter, no reset) ----
    __syncthreads();                               // all waves: stores drained
    if (tid == 0) {
      __builtin_amdgcn_fence(__ATOMIC_RELEASE, "agent");   // L2 writeback
      __hip_atomic_fetch_add(&bar[0], 1u, __ATOMIC_RELAXED,
                             __HIP_MEMORY_SCOPE_AGENT);
      const unsigned target = 256u * (unsigned)t;
      int guard = 0;
      while (__hip_atomic_load(&bar[0], __ATOMIC_RELAXED,
                               __HIP_MEMORY_SCOPE_AGENT) < target) {
        __builtin_amdgcn_s_sleep(1);
        if (++guard > 50000000) break;             // fail loud, not hung
      }
    }
    __syncthreads();
    __builtin_amdgcn_fence(__ATOMIC_ACQUIRE, "agent");     // L2/L1 invalidate
  }
}

// ---------------------------------------------------------------------------
// E[r][h] = exp(tanh(sum_k hs_r[k]*W_attn[h,k] + b_attn[h])), r = t*64+b.
// hse rows are contiguous (hs slabs 1..1024 flatten to exactly r-order).
// ---------------------------------------------------------------------------
__global__ __launch_bounds__(256) void k_attn(
    const f16_t* __restrict__ hse, const f16_t* __restrict__ WaT,
    const float* __restrict__ battn, f16_t* __restrict__ E) {
  const int w = threadIdx.x >> 6;
  const int L = threadIdx.x & 63;
  const int q = L >> 4, col = L & 15;
  const int m0 = blockIdx.x * 64 + w * 16;   // r rows
  const int n0 = blockIdx.y * 64;            // h cols

  f32x4 acc[4];
#pragma unroll
  for (int nt = 0; nt < 4; ++nt) acc[nt] = {0.f, 0.f, 0.f, 0.f};

#pragma unroll 4
  for (int kk = 0; kk < 16; ++kk) {          // K = 512
    half8 af = *(const half8*)(hse + (size_t)(m0 + col) * HDIM + kk * 32 + q * 8);
#pragma unroll
    for (int nt = 0; nt < 4; ++nt) {
      half8 bf = *(const half8*)(WaT +
          ((size_t)(kk * 4 + q) * HDIM + n0 + nt * 16 + col) * 8);
      acc[nt] = MFMA16(af, bf, acc[nt]);
    }
  }
#pragma unroll
  for (int nt = 0; nt < 4; ++nt) {
    const int h = n0 + nt * 16 + col;
    const float bias = battn[h];
#pragma unroll
    for (int r = 0; r < 4; ++r) {
      const int m = m0 + q * 4 + r;
      E[(size_t)m * HDIM + h] = (f16_t)__expf(tanh_fast(acc[nt][r] + bias));
    }
  }
}

__global__ __launch_bounds__(256) void k_pool(
    const f16_t* __restrict__ E, const f16_t* __restrict__ hse,
    float* __restrict__ pnum, float* __restrict__ pden) {
  const int b = blockIdx.x;                  // 0..63
  const int hc = blockIdx.y;                 // 0..1
  const int tc = blockIdx.z;                 // 0..3
  const int h = hc * 256 + threadIdx.x;
  float num = 0.f, den = 0.f;
#pragma unroll 4
  for (int tt = 0; tt < 256; ++tt) {
    const int t = tc * 256 + tt;
    const size_t idx = ((size_t)t * BATCH + b) * HDIM + h;
    const float e = (float)E[idx];
    const float hv = (float)hse[idx];
    den += e;
    num += e * hv;
  }
  const size_t pi = ((size_t)tc * BATCH + b) * HDIM + h;
  pnum[pi] = num;
  pden[pi] = den;
}

__global__ __launch_bounds__(256) void k_final(
    const float* __restrict__ pnum, const float* __restrict__ pden,
    float* __restrict__ out) {
  const int i = blockIdx.x * 256 + threadIdx.x;   // b*512+h
  float n = 0.f, d = 0.f;
#pragma unroll
  for (int z = 0; z < 4; ++z) {
    n += pnum[(size_t)z * 32768 + i];
    d += pden[(size_t)z * 32768 + i];
  }
  out[i] = n / d;
}

// ---------------------------------------------------------------------------
extern "C" void kernel_launch(void* const* d_in, const int* in_sizes, int n_in,
                              void* d_out, int out_size, void* d_ws, size_t ws_size,
                              hipStream_t stream) {
  const float* x   = (const float*)d_in[0];
  const float* Wih = (const float*)d_in[1];
  const float* Whh = (const float*)d_in[2];
  const float* bih = (const float*)d_in[3];
  const float* bhh = (const float*)d_in[4];
  const float* Wat = (const float*)d_in[5];
  const float* bat = (const float*)d_in[6];
  float* out = (float*)d_out;

  char* ws = (char*)d_ws;
  // regionA: xT (32MB) during recurrence, E (64MB) afterwards
  const size_t REGA_BYTES = (size_t)64 * 1024 * 1024;
  const size_t HS_BYTES = (size_t)(TLEN + 1) * BATCH * HDIM * sizeof(f16_t); // 67.2MB
  const size_t WAT_BYTES = (size_t)64 * HDIM * 8 * sizeof(f16_t);            // 512KB
  const size_t P_BYTES = (size_t)4 * BATCH * HDIM * sizeof(float);           // 512KB

  f16_t* xT = (f16_t*)ws;
  f16_t* E  = (f16_t*)ws;
  f16_t* hs = (f16_t*)(ws + REGA_BYTES);
  f16_t* WaT = (f16_t*)(ws + REGA_BYTES + HS_BYTES);
  float* pnum = (float*)(ws + REGA_BYTES + HS_BYTES + WAT_BYTES);
  float* pden = (float*)(ws + REGA_BYTES + HS_BYTES + WAT_BYTES + P_BYTES);
  unsigned int* bar = (unsigned int*)(ws + REGA_BYTES + HS_BYTES + WAT_BYTES + 2 * P_BYTES);

  // zero h0 slab + barrier counter (ws is re-poisoned 0xAA before every call)
  hipMemsetAsync(hs, 0, (size_t)BATCH * HDIM * sizeof(f16_t), stream);
  hipMemsetAsync(bar, 0, 64, stream);

  k_prep_x<<<dim3(TLEN), 256, 0, stream>>>(x, xT);
  k_prep_w<<<dim3(128), 256, 0, stream>>>(Wat, WaT);
  k_lstm<<<dim3(256), 128, 0, stream>>>(Whh, Wih, bih, bhh, xT, hs, bar);

  const f16_t* hse = hs + (size_t)BATCH * HDIM;   // slab 1 == reference hs[0]
  k_attn<<<dim3(1024, 8), 256, 0, stream>>>(hse, WaT, bat, E);
  k_pool<<<dim3(64, 2, 4), 256, 0, stream>>>(E, hse, pnum, pden);
  k_final<<<dim3(128), 256, 0, stream>>>(pnum, pden, out);
}

// Round 3
// 6551.311 us; speedup vs baseline: 2.0855x; 2.0855x over previous
//
#include <hip/hip_runtime.h>
#include <stdint.h>
#include <stddef.h>

// ---------------------------------------------------------------------------
// LSTM (B=64, T=1024, I=256, H=512) + attention pooling on MI355X (gfx950).
//   k_prep_x : x [B,T,I] fp32  -> xT [T][I/8][B][8] fp16 (MFMA B-layout)
//   k_prep_w : W_attn fp32     -> WaT [H/8][H][8] fp16  (MFMA B-layout)
//   k_lstm   : persistent recurrence, 256 blocks x 128 thr (1 block/CU).
//              Cross-XCD h exchange WITHOUT cache-maintenance fences:
//              h stores/loads carry sc0 sc1 (write-through / read-direct at
//              the LLC = agent coherence point). Barrier = vmcnt(0) +
//              __syncthreads + one RELAXED agent fetch_add + relaxed poll.
//              No buffer_wbl2 / buffer_inv per step (R2's 13 us/step killer).
//   k_attn   : E[t*64+b][h] = exp(tanh(hs @ W_attn^T + b_attn)) fp16
//   k_pool   : partial softmax-pool over T chunks
//   k_final  : context[b][h] = num/den  (fp32 out)
// ---------------------------------------------------------------------------

typedef _Float16 f16_t;
typedef _Float16 half8 __attribute__((ext_vector_type(8)));
typedef float f32x4 __attribute__((ext_vector_type(4)));

#define MFMA16(a, b, c) __builtin_amdgcn_mfma_f32_16x16x32_f16((a), (b), (c), 0, 0, 0)

static constexpr int BATCH = 64;
static constexpr int TLEN = 1024;
static constexpr int IDIM = 256;
static constexpr int HDIM = 512;

__device__ __forceinline__ float sigf(float x) { return 1.f / (1.f + __expf(-x)); }
__device__ __forceinline__ float tanh_fast(float x) {
  float e = __expf(2.f * fabsf(x));
  float t = 1.f - 2.f / (e + 1.f);
  return copysignf(t, x);
}
__device__ __forceinline__ half8 load_cvt8(const float* p) {
  f32x4 a = *(const f32x4*)p;
  f32x4 b = *(const f32x4*)(p + 4);
  half8 r;
#pragma unroll
  for (int j = 0; j < 4; ++j) { r[j] = (f16_t)a[j]; r[4 + j] = (f16_t)b[j]; }
  return r;
}

// ---------------------------------------------------------------------------
__global__ __launch_bounds__(256) void k_prep_x(const float* __restrict__ x,
                                                f16_t* __restrict__ xT) {
  __shared__ f16_t sx[64][IDIM + 8];
  const int t = blockIdx.x;
  const int tid = threadIdx.x;
#pragma unroll 4
  for (int b = 0; b < 64; ++b)
    sx[b][tid] = (f16_t)x[((size_t)b * TLEN + t) * IDIM + tid];
  __syncthreads();
#pragma unroll
  for (int it = 0; it < 8; ++it) {
    const int c = it * 256 + tid;      // c = kk4*64 + b
    const int b = c & 63, kk4 = c >> 6;
    half8 v = *(const half8*)&sx[b][kk4 * 8];
    *(half8*)(xT + (((size_t)t * 32 + kk4) * 64 + b) * 8) = v;
  }
}

__global__ __launch_bounds__(256) void k_prep_w(const float* __restrict__ Wa,
                                                f16_t* __restrict__ WaT) {
  const int id = blockIdx.x * 256 + threadIdx.x;   // 0..32767
  const int n = id & 511, kk4 = id >> 9;
  half8 v = load_cvt8(&Wa[(size_t)n * HDIM + kk4 * 8]);
  *(half8*)(WaT + ((size_t)kk4 * HDIM + n) * 8) = v;
}

// ---------------------------------------------------------------------------
// Recurrence. Block j: units u0=4*(j>>1)..+3, batch-half j&1; wave w covers
// b=(j&1)*32+w*16+col. M rows ordered [unit][gate]: C row q*4+r -> unit q,
// gate r => whole gate/cell update lane-local, c in fp32 register, all T.
// ---------------------------------------------------------------------------
__global__ __launch_bounds__(128, 1) void k_lstm(
    const float* __restrict__ Whh, const float* __restrict__ Wih,
    const float* __restrict__ bih, const float* __restrict__ bhh,
    const f16_t* __restrict__ xT, f16_t* __restrict__ hs,
    unsigned int* __restrict__ bar) {
  const int tid = threadIdx.x;
  const int w = tid >> 6;
  const int L = tid & 63;
  const int q = L >> 4, col = L & 15;
  const int u0 = (blockIdx.x >> 1) * 4;
  const int b = (blockIdx.x & 1) * 32 + w * 16 + col;
  const int myu = u0 + q;

  // Persistent A-fragments: A[m=lane&15][k=q*8+j]; m = unit_local*4 + gate.
  const int am = col;
  const int arow = (am & 3) * HDIM + u0 + (am >> 2);
  half8 wAh[16], wAx[8];
#pragma unroll
  for (int kk = 0; kk < 16; ++kk)
    wAh[kk] = load_cvt8(&Whh[(size_t)arow * HDIM + kk * 32 + q * 8]);
#pragma unroll
  for (int kk = 0; kk < 8; ++kk)
    wAx[kk] = load_cvt8(&Wih[(size_t)arow * IDIM + kk * 32 + q * 8]);

  float pb[4];
#pragma unroll
  for (int r = 0; r < 4; ++r) pb[r] = bih[r * HDIM + myu] + bhh[r * HDIM + myu];

  auto xgemm = [&](int t) {
    f32x4 a = {0.f, 0.f, 0.f, 0.f};
#pragma unroll
    for (int kk = 0; kk < 8; ++kk) {
      half8 bf = *(const half8*)(xT +
          (((size_t)(t - 1) * 32 + kk * 4 + q) * 64 + b) * 8);
      a = MFMA16(wAx[kk], bf, a);
    }
    return a;
  };

  float c = 0.f;
  f32x4 xacc = xgemm(1);
  for (int t = 1; t <= TLEN; ++t) {
    // ---- read h(t-1): 16 x dwordx4, sc0 sc1 = straight from LLC ----
    const f16_t* hbase = hs + ((size_t)(t - 1) * BATCH + b) * HDIM + q * 8;
    f32x4 hv[16];
    asm volatile(
        "global_load_dwordx4 %0, %16, off sc0 sc1\n\t"
        "global_load_dwordx4 %1, %16, off offset:64 sc0 sc1\n\t"
        "global_load_dwordx4 %2, %16, off offset:128 sc0 sc1\n\t"
        "global_load_dwordx4 %3, %16, off offset:192 sc0 sc1\n\t"
        "global_load_dwordx4 %4, %16, off offset:256 sc0 sc1\n\t"
        "global_load_dwordx4 %5, %16, off offset:320 sc0 sc1\n\t"
        "global_load_dwordx4 %6, %16, off offset:384 sc0 sc1\n\t"
        "global_load_dwordx4 %7, %16, off offset:448 sc0 sc1\n\t"
        "global_load_dwordx4 %8, %16, off offset:512 sc0 sc1\n\t"
        "global_load_dwordx4 %9, %16, off offset:576 sc0 sc1\n\t"
        "global_load_dwordx4 %10, %16, off offset:640 sc0 sc1\n\t"
        "global_load_dwordx4 %11, %16, off offset:704 sc0 sc1\n\t"
        "global_load_dwordx4 %12, %16, off offset:768 sc0 sc1\n\t"
        "global_load_dwordx4 %13, %16, off offset:832 sc0 sc1\n\t"
        "global_load_dwordx4 %14, %16, off offset:896 sc0 sc1\n\t"
        "global_load_dwordx4 %15, %16, off offset:960 sc0 sc1\n\t"
        "s_waitcnt vmcnt(0)"
        : "=&v"(hv[0]), "=&v"(hv[1]), "=&v"(hv[2]), "=&v"(hv[3]),
          "=&v"(hv[4]), "=&v"(hv[5]), "=&v"(hv[6]), "=&v"(hv[7]),
          "=&v"(hv[8]), "=&v"(hv[9]), "=&v"(hv[10]), "=&v"(hv[11]),
          "=&v"(hv[12]), "=&v"(hv[13]), "=&v"(hv[14]), "=&v"(hv[15])
        : "v"(hbase)
        : "memory");

    f32x4 acc = xacc;
#pragma unroll
    for (int kk = 0; kk < 16; ++kk)
      acc = MFMA16(wAh[kk], __builtin_bit_cast(half8, hv[kk]), acc);

    const float ig = sigf(acc[0] + pb[0]);
    const float fg = sigf(acc[1] + pb[1]);
    const float gg = tanh_fast(acc[2] + pb[2]);
    const float og = sigf(acc[3] + pb[3]);
    c = fg * c + ig * gg;
    const f16_t hval = (f16_t)(og * tanh_fast(c));

    // ---- write h(t): sc0 sc1 = write-through to LLC ----
    f16_t* hdst = hs + ((size_t)t * BATCH + b) * HDIM + myu;
    asm volatile("global_store_short %0, %1, off sc0 sc1"
                 :: "v"(hdst), "v"(hval) : "memory");

    // x-projection for the NEXT step overlaps the store-ack / barrier wait
    if (t < TLEN) xacc = xgemm(t + 1);

    // ---- barrier: drain own VMEM, block-sync, one relaxed agent atomic ----
    asm volatile("s_waitcnt vmcnt(0)" ::: "memory");
    __syncthreads();
    if (tid == 0) {
      __hip_atomic_fetch_add(&bar[0], 1u, __ATOMIC_RELAXED,
                             __HIP_MEMORY_SCOPE_AGENT);
      const unsigned target = 256u * (unsigned)t;
      unsigned v = 0;
      int guard = 0;
      do {
        asm volatile("global_load_dword %0, %1, off sc0 sc1\n\t"
                     "s_waitcnt vmcnt(0)"
                     : "=&v"(v) : "v"(bar) : "memory");
        if (v >= target) break;
        __builtin_amdgcn_s_sleep(2);
      } while (++guard < (1 << 25));
    }
    __syncthreads();
  }
}

// ---------------------------------------------------------------------------
__global__ __launch_bounds__(256) void k_attn(
    const f16_t* __restrict__ hse, const f16_t* __restrict__ WaT,
    const float* __restrict__ battn, f16_t* __restrict__ E) {
  const int w = threadIdx.x >> 6;
  const int L = threadIdx.x & 63;
  const int q = L >> 4, col = L & 15;
  const int m0 = blockIdx.x * 64 + w * 16;   // r rows (r = t*64+b)
  const int n0 = blockIdx.y * 64;            // h cols

  f32x4 acc[4];
#pragma unroll
  for (int nt = 0; nt < 4; ++nt) acc[nt] = {0.f, 0.f, 0.f, 0.f};

#pragma unroll 4
  for (int kk = 0; kk < 16; ++kk) {          // K = 512
    half8 af = *(const half8*)(hse + (size_t)(m0 + col) * HDIM + kk * 32 + q * 8);
#pragma unroll
    for (int nt = 0; nt < 4; ++nt) {
      half8 bf = *(const half8*)(WaT +
          ((size_t)(kk * 4 + q) * HDIM + n0 + nt * 16 + col) * 8);
      acc[nt] = MFMA16(af, bf, acc[nt]);
    }
  }
#pragma unroll
  for (int nt = 0; nt < 4; ++nt) {
    const int h = n0 + nt * 16 + col;
    const float bias = battn[h];
#pragma unroll
    for (int r = 0; r < 4; ++r) {
      const int m = m0 + q * 4 + r;
      E[(size_t)m * HDIM + h] = (f16_t)__expf(tanh_fast(acc[nt][r] + bias));
    }
  }
}

__global__ __launch_bounds__(256) void k_pool(
    const f16_t* __restrict__ E, const f16_t* __restrict__ hse,
    float* __restrict__ pnum, float* __restrict__ pden) {
  const int b = blockIdx.x;
  const int hc = blockIdx.y;
  const int tc = blockIdx.z;
  const int h = hc * 256 + threadIdx.x;
  float num = 0.f, den = 0.f;
#pragma unroll 4
  for (int tt = 0; tt < 256; ++tt) {
    const int t = tc * 256 + tt;
    const size_t idx = ((size_t)t * BATCH + b) * HDIM + h;
    const float e = (float)E[idx];
    const float hv = (float)hse[idx];
    den += e;
    num += e * hv;
  }
  const size_t pi = ((size_t)tc * BATCH + b) * HDIM + h;
  pnum[pi] = num;
  pden[pi] = den;
}

__global__ __launch_bounds__(256) void k_final(
    const float* __restrict__ pnum, const float* __restrict__ pden,
    float* __restrict__ out) {
  const int i = blockIdx.x * 256 + threadIdx.x;   // b*512+h
  float n = 0.f, d = 0.f;
#pragma unroll
  for (int z = 0; z < 4; ++z) {
    n += pnum[(size_t)z * 32768 + i];
    d += pden[(size_t)z * 32768 + i];
  }
  out[i] = n / d;
}

// ---------------------------------------------------------------------------
extern "C" void kernel_launch(void* const* d_in, const int* in_sizes, int n_in,
                              void* d_out, int out_size, void* d_ws, size_t ws_size,
                              hipStream_t stream) {
  const float* x   = (const float*)d_in[0];
  const float* Wih = (const float*)d_in[1];
  const float* Whh = (const float*)d_in[2];
  const float* bih = (const float*)d_in[3];
  const float* bhh = (const float*)d_in[4];
  const float* Wat = (const float*)d_in[5];
  const float* bat = (const float*)d_in[6];
  float* out = (float*)d_out;

  char* ws = (char*)d_ws;
  const size_t REGA_BYTES = (size_t)64 * 1024 * 1024;                        // xT then E
  const size_t HS_BYTES = (size_t)(TLEN + 1) * BATCH * HDIM * sizeof(f16_t); // 67.2MB
  const size_t WAT_BYTES = (size_t)64 * HDIM * 8 * sizeof(f16_t);            // 512KB
  const size_t P_BYTES = (size_t)4 * BATCH * HDIM * sizeof(float);           // 512KB

  f16_t* xT = (f16_t*)ws;
  f16_t* E  = (f16_t*)ws;
  f16_t* hs = (f16_t*)(ws + REGA_BYTES);
  f16_t* WaT = (f16_t*)(ws + REGA_BYTES + HS_BYTES);
  float* pnum = (float*)(ws + REGA_BYTES + HS_BYTES + WAT_BYTES);
  float* pden = (float*)(ws + REGA_BYTES + HS_BYTES + WAT_BYTES + P_BYTES);
  unsigned int* bar = (unsigned int*)(ws + REGA_BYTES + HS_BYTES + WAT_BYTES + 2 * P_BYTES);

  hipMemsetAsync(hs, 0, (size_t)BATCH * HDIM * sizeof(f16_t), stream);
  hipMemsetAsync(bar, 0, 64, stream);

  k_prep_x<<<dim3(TLEN), 256, 0, stream>>>(x, xT);
  k_prep_w<<<dim3(128), 256, 0, stream>>>(Wat, WaT);
  k_lstm<<<dim3(256), 128, 0, stream>>>(Whh, Wih, bih, bhh, xT, hs, bar);

  const f16_t* hse = hs + (size_t)BATCH * HDIM;   // slab 1 == reference hs[0]
  k_attn<<<dim3(1024, 8), 256, 0, stream>>>(hse, WaT, bat, E);
  k_pool<<<dim3(64, 2, 4), 256, 0, stream>>>(E, hse, pnum, pden);
  k_final<<<dim3(128), 256, 0, stream>>>(pnum, pden, out);
}

// Round 4
// 6376.266 us; speedup vs baseline: 2.1427x; 1.0275x over previous
//
#include <hip/hip_runtime.h>
#include <stdint.h>
#include <stddef.h>

// ---------------------------------------------------------------------------
// LSTM (B=64, T=1024, I=256, H=512) + attention pooling on MI355X (gfx950).
//   k_lstm v3: 64 blocks x 512 thr. Block (bg,ug) owns 16 batches x 32 units.
//   Batch groups (bg=0..3) are INDEPENDENT recurrence chains -> 4 separate
//   16-participant barriers (128B-apart counters), no global coupling.
//   h exchange via LLC-coherent ops only (sc0 sc1), no cache-maintenance
//   fences. h store: LDS-gathered -> 16 coalesced 64B full-line stores.
//   Dual MFMA accumulators halve the dependent-chain latency.
// ---------------------------------------------------------------------------

typedef _Float16 f16_t;
typedef _Float16 half8 __attribute__((ext_vector_type(8)));
typedef float f32x4 __attribute__((ext_vector_type(4)));

#define MFMA16(a, b, c) __builtin_amdgcn_mfma_f32_16x16x32_f16((a), (b), (c), 0, 0, 0)

static constexpr int BATCH = 64;
static constexpr int TLEN = 1024;
static constexpr int IDIM = 256;
static constexpr int HDIM = 512;

__device__ __forceinline__ float sigf(float x) { return 1.f / (1.f + __expf(-x)); }
__device__ __forceinline__ float tanh_fast(float x) {
  float e = __expf(2.f * fabsf(x));
  float t = 1.f - 2.f / (e + 1.f);
  return copysignf(t, x);
}
__device__ __forceinline__ half8 load_cvt8(const float* p) {
  f32x4 a = *(const f32x4*)p;
  f32x4 b = *(const f32x4*)(p + 4);
  half8 r;
#pragma unroll
  for (int j = 0; j < 4; ++j) { r[j] = (f16_t)a[j]; r[4 + j] = (f16_t)b[j]; }
  return r;
}

// ---------------------------------------------------------------------------
__global__ __launch_bounds__(256) void k_prep_x(const float* __restrict__ x,
                                                f16_t* __restrict__ xT) {
  __shared__ f16_t sx[64][IDIM + 8];
  const int t = blockIdx.x;
  const int tid = threadIdx.x;
#pragma unroll 4
  for (int b = 0; b < 64; ++b)
    sx[b][tid] = (f16_t)x[((size_t)b * TLEN + t) * IDIM + tid];
  __syncthreads();
#pragma unroll
  for (int it = 0; it < 8; ++it) {
    const int c = it * 256 + tid;      // c = kk4*64 + b
    const int b = c & 63, kk4 = c >> 6;
    half8 v = *(const half8*)&sx[b][kk4 * 8];
    *(half8*)(xT + (((size_t)t * 32 + kk4) * 64 + b) * 8) = v;
  }
}

__global__ __launch_bounds__(256) void k_prep_w(const float* __restrict__ Wa,
                                                f16_t* __restrict__ WaT) {
  const int id = blockIdx.x * 256 + threadIdx.x;   // 0..32767
  const int n = id & 511, kk4 = id >> 9;
  half8 v = load_cvt8(&Wa[(size_t)n * HDIM + kk4 * 8]);
  *(half8*)(WaT + ((size_t)kk4 * HDIM + n) * 8) = v;
}

// ---------------------------------------------------------------------------
// Recurrence. Block id = bg*16+ug: batches bg*16..+15, units ug*32..+31.
// Wave w: units u0=ug*32+w*4 .. +3. M rows [unit][gate]: C row q*4+r ->
// unit q, gate r => gate/cell update lane-local, c in fp32 reg for all T.
// ---------------------------------------------------------------------------
__global__ __launch_bounds__(512, 2) void k_lstm(
    const float* __restrict__ Whh, const float* __restrict__ Wih,
    const float* __restrict__ bih, const float* __restrict__ bhh,
    const f16_t* __restrict__ xT, f16_t* __restrict__ hs,
    unsigned int* __restrict__ bar) {
  const int tid = threadIdx.x;
  const int w = tid >> 6;
  const int L = tid & 63;
  const int q = L >> 4, col = L & 15;
  const int bg = blockIdx.x >> 4;            // 0..3  batch group
  const int ug = blockIdx.x & 15;            // 0..15 unit group
  const int u0 = ug * 32 + w * 4;
  const int b = bg * 16 + col;
  const int myu = u0 + q;
  unsigned int* mybar = bar + (size_t)bg * 32;   // 128B apart per group

  __shared__ __align__(16) f16_t hout[16][40];   // 80B row stride: 16B-aligned,
                                                 // 2-way-max LDS banks

  // Persistent A-fragments: A[m=lane&15][k=q*8+j]; m = unit_local*4 + gate.
  const int arow = (col & 3) * HDIM + u0 + (col >> 2);
  half8 wAh[16], wAx[8];
#pragma unroll
  for (int kk = 0; kk < 16; ++kk)
    wAh[kk] = load_cvt8(&Whh[(size_t)arow * HDIM + kk * 32 + q * 8]);
#pragma unroll
  for (int kk = 0; kk < 8; ++kk)
    wAx[kk] = load_cvt8(&Wih[(size_t)arow * IDIM + kk * 32 + q * 8]);

  float pb[4];
#pragma unroll
  for (int r = 0; r < 4; ++r) pb[r] = bih[r * HDIM + myu] + bhh[r * HDIM + myu];

  auto xgemm = [&](int t) {
    f32x4 a = {0.f, 0.f, 0.f, 0.f};
#pragma unroll
    for (int kk = 0; kk < 8; ++kk) {
      half8 bf = *(const half8*)(xT +
          (((size_t)(t - 1) * 32 + kk * 4 + q) * 64 + b) * 8);
      a = MFMA16(wAx[kk], bf, a);
    }
    return a;
  };

  float c = 0.f;
  f32x4 xacc = xgemm(1);
  for (int t = 1; t <= TLEN; ++t) {
    // ---- read h(t-1): 16 x dwordx4 sc0 sc1 (straight from LLC) ----
    const f16_t* hbase = hs + ((size_t)(t - 1) * BATCH + b) * HDIM + q * 8;
    f32x4 hv[16];
    asm volatile(
        "global_load_dwordx4 %0, %16, off sc0 sc1\n\t"
        "global_load_dwordx4 %1, %16, off offset:64 sc0 sc1\n\t"
        "global_load_dwordx4 %2, %16, off offset:128 sc0 sc1\n\t"
        "global_load_dwordx4 %3, %16, off offset:192 sc0 sc1\n\t"
        "global_load_dwordx4 %4, %16, off offset:256 sc0 sc1\n\t"
        "global_load_dwordx4 %5, %16, off offset:320 sc0 sc1\n\t"
        "global_load_dwordx4 %6, %16, off offset:384 sc0 sc1\n\t"
        "global_load_dwordx4 %7, %16, off offset:448 sc0 sc1\n\t"
        "global_load_dwordx4 %8, %16, off offset:512 sc0 sc1\n\t"
        "global_load_dwordx4 %9, %16, off offset:576 sc0 sc1\n\t"
        "global_load_dwordx4 %10, %16, off offset:640 sc0 sc1\n\t"
        "global_load_dwordx4 %11, %16, off offset:704 sc0 sc1\n\t"
        "global_load_dwordx4 %12, %16, off offset:768 sc0 sc1\n\t"
        "global_load_dwordx4 %13, %16, off offset:832 sc0 sc1\n\t"
        "global_load_dwordx4 %14, %16, off offset:896 sc0 sc1\n\t"
        "global_load_dwordx4 %15, %16, off offset:960 sc0 sc1\n\t"
        "s_waitcnt vmcnt(0)"
        : "=&v"(hv[0]), "=&v"(hv[1]), "=&v"(hv[2]), "=&v"(hv[3]),
          "=&v"(hv[4]), "=&v"(hv[5]), "=&v"(hv[6]), "=&v"(hv[7]),
          "=&v"(hv[8]), "=&v"(hv[9]), "=&v"(hv[10]), "=&v"(hv[11]),
          "=&v"(hv[12]), "=&v"(hv[13]), "=&v"(hv[14]), "=&v"(hv[15])
        : "v"(hbase)
        : "memory");

    // dual accumulators: halve the dependent-MFMA chain
    f32x4 a0 = xacc, a1 = {0.f, 0.f, 0.f, 0.f};
#pragma unroll
    for (int kk = 0; kk < 16; kk += 2) {
      a0 = MFMA16(wAh[kk], __builtin_bit_cast(half8, hv[kk]), a0);
      a1 = MFMA16(wAh[kk + 1], __builtin_bit_cast(half8, hv[kk + 1]), a1);
    }
    const f32x4 acc = a0 + a1;

    const float ig = sigf(acc[0] + pb[0]);
    const float fg = sigf(acc[1] + pb[1]);
    const float gg = tanh_fast(acc[2] + pb[2]);
    const float og = sigf(acc[3] + pb[3]);
    c = fg * c + ig * gg;
    hout[col][w * 4 + q] = (f16_t)(og * tanh_fast(c));

    __syncthreads();                           // hout complete

    // ---- wave 0: 16 coalesced 64B line stores (4 lanes x dwordx4 each) ----
    if (w == 0) {
      const int lb = L >> 2, q4 = L & 3;
      f32x4 v = *(const f32x4*)&hout[lb][q4 * 8];
      f16_t* dst = hs + ((size_t)t * BATCH + bg * 16 + lb) * HDIM + ug * 32 + q4 * 8;
      asm volatile("global_store_dwordx4 %0, %1, off sc0 sc1"
                   :: "v"(dst), "v"(v) : "memory");
    }

    // x-projection for the NEXT step: overlaps store-ack + barrier
    if (t < TLEN) xacc = xgemm(t + 1);

    if (tid == 0) {
      asm volatile("s_waitcnt vmcnt(0)" ::: "memory");   // stores at LLC
      __hip_atomic_fetch_add(mybar, 1u, __ATOMIC_RELAXED,
                             __HIP_MEMORY_SCOPE_AGENT);
      const unsigned target = 16u * (unsigned)t;
      unsigned v = 0;
      int guard = 0;
      do {
        asm volatile("global_load_dword %0, %1, off sc0 sc1\n\t"
                     "s_waitcnt vmcnt(0)"
                     : "=&v"(v) : "v"(mybar) : "memory");
        if (v >= target) break;
        __builtin_amdgcn_s_sleep(1);
      } while (++guard < (1 << 25));
    }
    __syncthreads();
  }
}

// ---------------------------------------------------------------------------
__global__ __launch_bounds__(256) void k_attn(
    const f16_t* __restrict__ hse, const f16_t* __restrict__ WaT,
    const float* __restrict__ battn, f16_t* __restrict__ E) {
  const int w = threadIdx.x >> 6;
  const int L = threadIdx.x & 63;
  const int q = L >> 4, col = L & 15;
  const int m0 = blockIdx.x * 64 + w * 16;   // r rows (r = t*64+b)
  const int n0 = blockIdx.y * 64;            // h cols

  f32x4 acc[4];
#pragma unroll
  for (int nt = 0; nt < 4; ++nt) acc[nt] = {0.f, 0.f, 0.f, 0.f};

#pragma unroll 4
  for (int kk = 0; kk < 16; ++kk) {          // K = 512
    half8 af = *(const half8*)(hse + (size_t)(m0 + col) * HDIM + kk * 32 + q * 8);
#pragma unroll
    for (int nt = 0; nt < 4; ++nt) {
      half8 bf = *(const half8*)(WaT +
          ((size_t)(kk * 4 + q) * HDIM + n0 + nt * 16 + col) * 8);
      acc[nt] = MFMA16(af, bf, acc[nt]);
    }
  }
#pragma unroll
  for (int nt = 0; nt < 4; ++nt) {
    const int h = n0 + nt * 16 + col;
    const float bias = battn[h];
#pragma unroll
    for (int r = 0; r < 4; ++r) {
      const int m = m0 + q * 4 + r;
      E[(size_t)m * HDIM + h] = (f16_t)__expf(tanh_fast(acc[nt][r] + bias));
    }
  }
}

__global__ __launch_bounds__(256) void k_pool(
    const f16_t* __restrict__ E, const f16_t* __restrict__ hse,
    float* __restrict__ pnum, float* __restrict__ pden) {
  const int b = blockIdx.x;
  const int hc = blockIdx.y;
  const int tc = blockIdx.z;
  const int h = hc * 256 + threadIdx.x;
  float num = 0.f, den = 0.f;
#pragma unroll 4
  for (int tt = 0; tt < 256; ++tt) {
    const int t = tc * 256 + tt;
    const size_t idx = ((size_t)t * BATCH + b) * HDIM + h;
    const float e = (float)E[idx];
    const float hv = (float)hse[idx];
    den += e;
    num += e * hv;
  }
  const size_t pi = ((size_t)tc * BATCH + b) * HDIM + h;
  pnum[pi] = num;
  pden[pi] = den;
}

__global__ __launch_bounds__(256) void k_final(
    const float* __restrict__ pnum, const float* __restrict__ pden,
    float* __restrict__ out) {
  const int i = blockIdx.x * 256 + threadIdx.x;   // b*512+h
  float n = 0.f, d = 0.f;
#pragma unroll
  for (int z = 0; z < 4; ++z) {
    n += pnum[(size_t)z * 32768 + i];
    d += pden[(size_t)z * 32768 + i];
  }
  out[i] = n / d;
}

// ---------------------------------------------------------------------------
extern "C" void kernel_launch(void* const* d_in, const int* in_sizes, int n_in,
                              void* d_out, int out_size, void* d_ws, size_t ws_size,
                              hipStream_t stream) {
  const float* x   = (const float*)d_in[0];
  const float* Wih = (const float*)d_in[1];
  const float* Whh = (const float*)d_in[2];
  const float* bih = (const float*)d_in[3];
  const float* bhh = (const float*)d_in[4];
  const float* Wat = (const float*)d_in[5];
  const float* bat = (const float*)d_in[6];
  float* out = (float*)d_out;

  char* ws = (char*)d_ws;
  const size_t REGA_BYTES = (size_t)64 * 1024 * 1024;                        // xT then E
  const size_t HS_BYTES = (size_t)(TLEN + 1) * BATCH * HDIM * sizeof(f16_t); // 67.2MB
  const size_t WAT_BYTES = (size_t)64 * HDIM * 8 * sizeof(f16_t);            // 512KB
  const size_t P_BYTES = (size_t)4 * BATCH * HDIM * sizeof(float);           // 512KB

  f16_t* xT = (f16_t*)ws;
  f16_t* E  = (f16_t*)ws;
  f16_t* hs = (f16_t*)(ws + REGA_BYTES);
  f16_t* WaT = (f16_t*)(ws + REGA_BYTES + HS_BYTES);
  float* pnum = (float*)(ws + REGA_BYTES + HS_BYTES + WAT_BYTES);
  float* pden = (float*)(ws + REGA_BYTES + HS_BYTES + WAT_BYTES + P_BYTES);
  unsigned int* bar = (unsigned int*)(ws + REGA_BYTES + HS_BYTES + WAT_BYTES + 2 * P_BYTES);

  hipMemsetAsync(hs, 0, (size_t)BATCH * HDIM * sizeof(f16_t), stream);
  hipMemsetAsync(bar, 0, 512, stream);   // 4 groups x 128B counter lines

  k_prep_x<<<dim3(TLEN), 256, 0, stream>>>(x, xT);
  k_prep_w<<<dim3(128), 256, 0, stream>>>(Wat, WaT);
  k_lstm<<<dim3(64), 512, 0, stream>>>(Whh, Wih, bih, bhh, xT, hs, bar);

  const f16_t* hse = hs + (size_t)BATCH * HDIM;   // slab 1 == reference hs[0]
  k_attn<<<dim3(1024, 8), 256, 0, stream>>>(hse, WaT, bat, E);
  k_pool<<<dim3(64, 2, 4), 256, 0, stream>>>(E, hse, pnum, pden);
  k_final<<<dim3(128), 256, 0, stream>>>(pnum, pden, out);
}

// Round 5
// 3174.892 us; speedup vs baseline: 4.3033x; 2.0083x over previous
//
#include <hip/hip_runtime.h>
#include <stdint.h>
#include <stddef.h>

// ---------------------------------------------------------------------------
// LSTM (B=64, T=1024, I=256, H=512) + attention pooling on MI355X (gfx950).
//   k_lstm v4: 64 blocks x 512 thr; block (bg,ug) = 16 batches x 32 units.
//   KEY CHANGE vs R4: h(t-1) is coop-loaded ONCE per block (16 KB, 256
//   coherent 64B requests) into LDS; all 8 waves broadcast-read fragments
//   from LDS. R3/R4 issued 131072 coherent req/step (8x duplicated) and both
//   sat at ~6 us/step => LLC coherent-request-rate bound. This is 8x fewer.
//   Barrier: per-block flag words (no RMW): producer stores h (sc0 sc1),
//   vmcnt(0), stores flag=t; consumers poll the 64B flag line w/ 16 lanes +
//   ballot. 4 independent batch-group chains, 16 participants each.
// ---------------------------------------------------------------------------

typedef _Float16 f16_t;
typedef _Float16 half8 __attribute__((ext_vector_type(8)));
typedef float f32x4 __attribute__((ext_vector_type(4)));

#define MFMA16(a, b, c) __builtin_amdgcn_mfma_f32_16x16x32_f16((a), (b), (c), 0, 0, 0)

static constexpr int BATCH = 64;
static constexpr int TLEN = 1024;
static constexpr int IDIM = 256;
static constexpr int HDIM = 512;

__device__ __forceinline__ float sigf(float x) { return 1.f / (1.f + __expf(-x)); }
__device__ __forceinline__ float tanh_fast(float x) {
  float e = __expf(2.f * fabsf(x));
  float t = 1.f - 2.f / (e + 1.f);
  return copysignf(t, x);
}
__device__ __forceinline__ half8 load_cvt8(const float* p) {
  f32x4 a = *(const f32x4*)p;
  f32x4 b = *(const f32x4*)(p + 4);
  half8 r;
#pragma unroll
  for (int j = 0; j < 4; ++j) { r[j] = (f16_t)a[j]; r[4 + j] = (f16_t)b[j]; }
  return r;
}

// ---------------------------------------------------------------------------
__global__ __launch_bounds__(256) void k_prep_x(const float* __restrict__ x,
                                                f16_t* __restrict__ xT) {
  __shared__ f16_t sx[64][IDIM + 8];
  const int t = blockIdx.x;
  const int tid = threadIdx.x;
#pragma unroll 4
  for (int b = 0; b < 64; ++b)
    sx[b][tid] = (f16_t)x[((size_t)b * TLEN + t) * IDIM + tid];
  __syncthreads();
#pragma unroll
  for (int it = 0; it < 8; ++it) {
    const int c = it * 256 + tid;      // c = kk4*64 + b
    const int b = c & 63, kk4 = c >> 6;
    half8 v = *(const half8*)&sx[b][kk4 * 8];
    *(half8*)(xT + (((size_t)t * 32 + kk4) * 64 + b) * 8) = v;
  }
}

__global__ __launch_bounds__(256) void k_prep_w(const float* __restrict__ Wa,
                                                f16_t* __restrict__ WaT) {
  const int id = blockIdx.x * 256 + threadIdx.x;   // 0..32767
  const int n = id & 511, kk4 = id >> 9;
  half8 v = load_cvt8(&Wa[(size_t)n * HDIM + kk4 * 8]);
  *(half8*)(WaT + ((size_t)kk4 * HDIM + n) * 8) = v;
}

// ---------------------------------------------------------------------------
// Recurrence. Block id = bg*16+ug: batches bg*16..+15, units ug*32..+31.
// Wave w: units u0=ug*32+w*4..+3. M rows [unit][gate]: C row q*4+r -> unit q,
// gate r => gate/cell update lane-local, c in fp32 register for all T.
// ---------------------------------------------------------------------------
__global__ __launch_bounds__(512, 2) void k_lstm(
    const float* __restrict__ Whh, const float* __restrict__ Wih,
    const float* __restrict__ bih, const float* __restrict__ bhh,
    const f16_t* __restrict__ xT, f16_t* __restrict__ hs,
    unsigned int* __restrict__ bar) {
  const int tid = threadIdx.x;
  const int w = tid >> 6;
  const int L = tid & 63;
  const int q = L >> 4, col = L & 15;
  const int bg = blockIdx.x >> 4;            // 0..3  batch group (chain)
  const int ug = blockIdx.x & 15;            // 0..15 unit group
  const int u0 = ug * 32 + w * 4;
  const int b = bg * 16 + col;
  const int myu = u0 + q;
  unsigned int* chainflags = bar + (size_t)bg * 16;   // 64B line, 16 dwords

  __shared__ __align__(16) f16_t hin[16][520];  // h(t-1): 1040B stride -> 2-way
  __shared__ __align__(16) f16_t hout[16][40];  // block's h(t) chunk

  // Persistent A-fragments: A[m=lane&15][k=q*8+j]; m = unit_local*4 + gate.
  const int arow = (col & 3) * HDIM + u0 + (col >> 2);
  half8 wAh[16], wAx[8];
#pragma unroll
  for (int kk = 0; kk < 16; ++kk)
    wAh[kk] = load_cvt8(&Whh[(size_t)arow * HDIM + kk * 32 + q * 8]);
#pragma unroll
  for (int kk = 0; kk < 8; ++kk)
    wAx[kk] = load_cvt8(&Wih[(size_t)arow * IDIM + kk * 32 + q * 8]);

  float pb[4];
#pragma unroll
  for (int r = 0; r < 4; ++r) pb[r] = bih[r * HDIM + myu] + bhh[r * HDIM + myu];

  auto xgemm = [&](int t) {
    f32x4 a = {0.f, 0.f, 0.f, 0.f};
#pragma unroll
    for (int kk = 0; kk < 8; ++kk) {
      half8 bf = *(const half8*)(xT +
          (((size_t)(t - 1) * 32 + kk * 4 + q) * 64 + b) * 8);
      a = MFMA16(wAx[kk], bf, a);
    }
    return a;
  };

  // coop-load assignment: tid -> batch lb = tid>>5, 32B chunk ck = tid&31
  const int lb = tid >> 5, ck = tid & 31;

  float c = 0.f;
  f32x4 xacc = xgemm(1);
  for (int t = 1; t <= TLEN; ++t) {
    // ---- wait for all 16 producer flags >= t-1 (each wave independently) ---
    if (t > 1) {
      const unsigned tgt = (unsigned)(t - 1);
      const unsigned int* fl = chainflags + (L & 15);
      int guard = 0;
      for (;;) {
        unsigned v;
        asm volatile("global_load_dword %0, %1, off sc0 sc1\n\t"
                     "s_waitcnt vmcnt(0)"
                     : "=&v"(v) : "v"(fl) : "memory");
        const bool ok = (L < 16) ? (v >= tgt) : true;
        if (__ballot(ok) == ~0ull) break;
        __builtin_amdgcn_s_sleep(2);
        if (++guard > (1 << 25)) break;        // fail loud, not hung
      }
    }

    // ---- coop-load h(t-1): ONE 16KB coherent read per block -> LDS ----
    {
      const f16_t* src = hs + ((size_t)(t - 1) * BATCH + bg * 16 + lb) * HDIM
                         + ck * 16;            // 32B per thread
      f32x4 v0, v1;
      asm volatile("global_load_dwordx4 %0, %2, off sc0 sc1\n\t"
                   "global_load_dwordx4 %1, %2, off offset:16 sc0 sc1\n\t"
                   "s_waitcnt vmcnt(0)"
                   : "=&v"(v0), "=&v"(v1) : "v"(src) : "memory");
      *(f32x4*)&hin[lb][ck * 16] = v0;
      *(f32x4*)&hin[lb][ck * 16 + 8] = v1;
    }
    __syncthreads();                           // hin complete

    // ---- MFMA: B-frags broadcast-read from LDS, dual accumulators ----
    f32x4 a0 = xacc, a1 = {0.f, 0.f, 0.f, 0.f};
#pragma unroll
    for (int kk = 0; kk < 16; kk += 2) {
      half8 b0 = *(const half8*)&hin[col][kk * 32 + q * 8];
      half8 b1 = *(const half8*)&hin[col][(kk + 1) * 32 + q * 8];
      a0 = MFMA16(wAh[kk], b0, a0);
      a1 = MFMA16(wAh[kk + 1], b1, a1);
    }
    const f32x4 acc = a0 + a1;

    const float ig = sigf(acc[0] + pb[0]);
    const float fg = sigf(acc[1] + pb[1]);
    const float gg = tanh_fast(acc[2] + pb[2]);
    const float og = sigf(acc[3] + pb[3]);
    c = fg * c + ig * gg;
    hout[col][w * 4 + q] = (f16_t)(og * tanh_fast(c));

    __syncthreads();                           // hout ready, hin consumed

    // ---- wave 0: 16 coalesced 64B stores + drain + flag=t ----
    if (w == 0) {
      const int sb = L >> 2, q4 = L & 3;
      f32x4 v = *(const f32x4*)&hout[sb][q4 * 8];
      f16_t* dst = hs + ((size_t)t * BATCH + bg * 16 + sb) * HDIM
                   + ug * 32 + q4 * 8;
      asm volatile("global_store_dwordx4 %0, %1, off sc0 sc1"
                   :: "v"(dst), "v"(v) : "memory");
      asm volatile("s_waitcnt vmcnt(0)" ::: "memory");
      if (L == 0) {
        unsigned tv = (unsigned)t;
        asm volatile("global_store_dword %0, %1, off sc0 sc1"
                     :: "v"(chainflags + ug), "v"(tv) : "memory");
      }
    }

    // x-projection for the NEXT step: overlaps other blocks' compute
    if (t < TLEN) xacc = xgemm(t + 1);
  }
}

// ---------------------------------------------------------------------------
__global__ __launch_bounds__(256) void k_attn(
    const f16_t* __restrict__ hse, const f16_t* __restrict__ WaT,
    const float* __restrict__ battn, f16_t* __restrict__ E) {
  const int w = threadIdx.x >> 6;
  const int L = threadIdx.x & 63;
  const int q = L >> 4, col = L & 15;
  const int m0 = blockIdx.x * 64 + w * 16;   // r rows (r = t*64+b)
  const int n0 = blockIdx.y * 64;            // h cols

  f32x4 acc[4];
#pragma unroll
  for (int nt = 0; nt < 4; ++nt) acc[nt] = {0.f, 0.f, 0.f, 0.f};

#pragma unroll 4
  for (int kk = 0; kk < 16; ++kk) {          // K = 512
    half8 af = *(const half8*)(hse + (size_t)(m0 + col) * HDIM + kk * 32 + q * 8);
#pragma unroll
    for (int nt = 0; nt < 4; ++nt) {
      half8 bf = *(const half8*)(WaT +
          ((size_t)(kk * 4 + q) * HDIM + n0 + nt * 16 + col) * 8);
      acc[nt] = MFMA16(af, bf, acc[nt]);
    }
  }
#pragma unroll
  for (int nt = 0; nt < 4; ++nt) {
    const int h = n0 + nt * 16 + col;
    const float bias = battn[h];
#pragma unroll
    for (int r = 0; r < 4; ++r) {
      const int m = m0 + q * 4 + r;
      E[(size_t)m * HDIM + h] = (f16_t)__expf(tanh_fast(acc[nt][r] + bias));
    }
  }
}

__global__ __launch_bounds__(256) void k_pool(
    const f16_t* __restrict__ E, const f16_t* __restrict__ hse,
    float* __restrict__ pnum, float* __restrict__ pden) {
  const int b = blockIdx.x;
  const int hc = blockIdx.y;
  const int tc = blockIdx.z;
  const int h = hc * 256 + threadIdx.x;
  float num = 0.f, den = 0.f;
#pragma unroll 4
  for (int tt = 0; tt < 256; ++tt) {
    const int t = tc * 256 + tt;
    const size_t idx = ((size_t)t * BATCH + b) * HDIM + h;
    const float e = (float)E[idx];
    const float hv = (float)hse[idx];
    den += e;
    num += e * hv;
  }
  const size_t pi = ((size_t)tc * BATCH + b) * HDIM + h;
  pnum[pi] = num;
  pden[pi] = den;
}

__global__ __launch_bounds__(256) void k_final(
    const float* __restrict__ pnum, const float* __restrict__ pden,
    float* __restrict__ out) {
  const int i = blockIdx.x * 256 + threadIdx.x;   // b*512+h
  float n = 0.f, d = 0.f;
#pragma unroll
  for (int z = 0; z < 4; ++z) {
    n += pnum[(size_t)z * 32768 + i];
    d += pden[(size_t)z * 32768 + i];
  }
  out[i] = n / d;
}

// ---------------------------------------------------------------------------
extern "C" void kernel_launch(void* const* d_in, const int* in_sizes, int n_in,
                              void* d_out, int out_size, void* d_ws, size_t ws_size,
                              hipStream_t stream) {
  const float* x   = (const float*)d_in[0];
  const float* Wih = (const float*)d_in[1];
  const float* Whh = (const float*)d_in[2];
  const float* bih = (const float*)d_in[3];
  const float* bhh = (const float*)d_in[4];
  const float* Wat = (const float*)d_in[5];
  const float* bat = (const float*)d_in[6];
  float* out = (float*)d_out;

  char* ws = (char*)d_ws;
  const size_t REGA_BYTES = (size_t)64 * 1024 * 1024;                        // xT then E
  const size_t HS_BYTES = (size_t)(TLEN + 1) * BATCH * HDIM * sizeof(f16_t); // 67.2MB
  const size_t WAT_BYTES = (size_t)64 * HDIM * 8 * sizeof(f16_t);            // 512KB
  const size_t P_BYTES = (size_t)4 * BATCH * HDIM * sizeof(float);           // 512KB

  f16_t* xT = (f16_t*)ws;
  f16_t* E  = (f16_t*)ws;
  f16_t* hs = (f16_t*)(ws + REGA_BYTES);
  f16_t* WaT = (f16_t*)(ws + REGA_BYTES + HS_BYTES);
  float* pnum = (float*)(ws + REGA_BYTES + HS_BYTES + WAT_BYTES);
  float* pden = (float*)(ws + REGA_BYTES + HS_BYTES + WAT_BYTES + P_BYTES);
  unsigned int* bar = (unsigned int*)(ws + REGA_BYTES + HS_BYTES + WAT_BYTES + 2 * P_BYTES);

  hipMemsetAsync(hs, 0, (size_t)BATCH * HDIM * sizeof(f16_t), stream);
  hipMemsetAsync(bar, 0, 512, stream);   // 4 chains x 16 flag dwords

  k_prep_x<<<dim3(TLEN), 256, 0, stream>>>(x, xT);
  k_prep_w<<<dim3(128), 256, 0, stream>>>(Wat, WaT);
  k_lstm<<<dim3(64), 512, 0, stream>>>(Whh, Wih, bih, bhh, xT, hs, bar);

  const f16_t* hse = hs + (size_t)BATCH * HDIM;   // slab 1 == reference hs[0]
  k_attn<<<dim3(1024, 8), 256, 0, stream>>>(hse, WaT, bat, E);
  k_pool<<<dim3(64, 2, 4), 256, 0, stream>>>(E, hse, pnum, pden);
  k_final<<<dim3(128), 256, 0, stream>>>(pnum, pden, out);
}